// Round 9
// baseline (119.504 us; speedup 1.0000x reference)
//
#include <hip/hip_runtime.h>
#include <math.h>

#define EPSF 1e-9f

typedef float v4f __attribute__((ext_vector_type(4)));

// ws layout:
//   [0)     acc[4] floats: 0=id_num 1=id_cnt 2=kl_sum   (memset each launch)
//   [256)   agg_g [256][64] float (64 KB)               (memset each launch)

// ---------------------------------------------------------------------------
// Stream: GRID-STRIDE LINEAR. 1024 blocks x 512 thr (4/CU co-resident).
// b = (bid>>1)&255 constant per block; v = (bid&1)*2048 + tid*4 constant per
// lane. Per-step advance = 2M floats = 2 t-slabs; 24 steps cover t=0..47.
// Labels pair at +1 slab (row t+1, same b,v); labels are exact one-hots so
// the NLL value is the same lane's out float4 -> no gather. Each block builds
// its own route->slot table in LDS (prep kernel eliminated): table[rid] =
// first-occurrence candidate slot. dist partials scatter via table into LDS
// agg_s -> global agg_g. out_ids: normal loads (L3-resident). labels: nt.
// ---------------------------------------------------------------------------
__global__ __launch_bounds__(512) void e2e3_stream(
    const float* __restrict__ out_ids,        // [48,256,4096]
    const float* __restrict__ trg_labels,     // [50,256,4096]
    const int*   __restrict__ candi_ids,      // [256,64]
    const int*   __restrict__ routes,         // [256,4096]
    float* __restrict__ agg_g,                // [256,64]
    float* __restrict__ acc)
{
    const int bid  = blockIdx.x;
    const int tid  = threadIdx.x;
    const int wave = tid >> 6;
    const int lane = tid & 63;

    const int b = (bid >> 1) & 255;                 // constant per block
    const int v = (bid & 1) * 2048 + tid * 4;       // constant per lane

    __shared__ int   table[1024];
    __shared__ float agg_s[64];
    __shared__ float red[2][8];

    // build this b's route->slot table (first-occurrence dedup)
    table[tid]       = 64;
    table[tid + 512] = 64;
    if (tid < 64) agg_s[tid] = 0.f;
    __syncthreads();
    if (tid < 64) atomicMin(&table[candi_ids[b * 64 + tid]], tid);
    __syncthreads();

    // this lane's 4 slots (fixed for all steps)
    const int4 rt = *reinterpret_cast<const int4*>(routes + (size_t)b * 4096 + v);
    const int tu0 = table[rt.x], tu1 = table[rt.y];
    const int tu2 = table[rt.z], tu3 = table[rt.w];

    const size_t STEP = (size_t)2097152;            // floats per step (2 t-slabs)
    const size_t e0   = (size_t)(bid * 512 + tid) * 4;
    const float* op = out_ids + e0;
    const float* lp = trg_labels + e0 + 1048576;    // +1 t-slab => row t+1

    float s0 = 0.f, s1 = 0.f, s2 = 0.f, s3 = 0.f;   // per-lane dist partials
    float idnum = 0.f, idcnt = 0.f;

    v4f oa = *reinterpret_cast<const v4f*>(op);
    v4f la = __builtin_nontemporal_load(reinterpret_cast<const v4f*>(lp));
    v4f ob = *reinterpret_cast<const v4f*>(op + STEP);
    v4f lb = __builtin_nontemporal_load(reinterpret_cast<const v4f*>(lp + STEP));

    for (int s = 0; s < 24; ++s) {
        v4f oc = (v4f)(0.f), lc = (v4f)(0.f);
        if (s < 22) {
            oc = *reinterpret_cast<const v4f*>(op + (size_t)(s + 2) * STEP);
            lc = __builtin_nontemporal_load(
                     reinterpret_cast<const v4f*>(lp + (size_t)(s + 2) * STEP));
        }
        s0 += oa.x; s1 += oa.y; s2 += oa.z; s3 += oa.w;
        if (la.x > 0.5f) { idnum -= logf(fmaxf(oa.x, EPSF)); idcnt += 1.f; }
        if (la.y > 0.5f) { idnum -= logf(fmaxf(oa.y, EPSF)); idcnt += 1.f; }
        if (la.z > 0.5f) { idnum -= logf(fmaxf(oa.z, EPSF)); idcnt += 1.f; }
        if (la.w > 0.5f) { idnum -= logf(fmaxf(oa.w, EPSF)); idcnt += 1.f; }
        oa = ob; la = lb; ob = oc; lb = lc;
    }

    // scatter per-lane dist sums (valid slots only, ~6% density)
    if (tu0 < 64) atomicAdd(&agg_s[tu0], s0);
    if (tu1 < 64) atomicAdd(&agg_s[tu1], s1);
    if (tu2 < 64) atomicAdd(&agg_s[tu2], s2);
    if (tu3 < 64) atomicAdd(&agg_s[tu3], s3);

    #pragma unroll
    for (int off = 32; off >= 1; off >>= 1) {
        idnum += __shfl_down(idnum, off, 64);
        idcnt += __shfl_down(idcnt, off, 64);
    }
    if (lane == 0) { red[0][wave] = idnum; red[1][wave] = idcnt; }
    __syncthreads();
    if (tid == 0) {
        float a = 0.f, c = 0.f;
        #pragma unroll
        for (int w = 0; w < 8; ++w) { a += red[0][w]; c += red[1][w]; }
        atomicAdd(&acc[0], a);
        atomicAdd(&acc[1], c);
    }
    if (tid < 64) atomicAdd(&agg_g[b * 64 + tid], agg_s[tid]);
}

// ---------------------------------------------------------------------------
// KL finalize (dedup + Pm + Pb + KL fused): grid 256 x 64 (one wave per b).
// ---------------------------------------------------------------------------
__global__ __launch_bounds__(64) void e2e3_kl2(
    const float* __restrict__ selector_probs,   // [256,64]
    const int*   __restrict__ candi_ids,        // [256,64]
    const float* __restrict__ agg_g,            // [256,64]
    float* __restrict__ acc)
{
    const int b = blockIdx.x;
    const int u = threadIdx.x;

    __shared__ int table[1024];
    __shared__ int ids_s[64];
    __shared__ int rep_s[64];

    #pragma unroll
    for (int i = 0; i < 16; ++i) table[u + i * 64] = 64;
    ids_s[u] = candi_ids[b * 64 + u];
    __syncthreads();
    atomicMin(&table[ids_s[u]], u);
    __syncthreads();
    const int rep = table[ids_s[u]];
    rep_s[u] = rep;
    const float va = (rep == u) ? 1.f : 0.f;
    __syncthreads();

    // Pm scatter: sum selector probs whose representative is slot u
    float pm = 0.f;
    for (int i = 0; i < 64; ++i)
        if (rep_s[i] == u) pm += selector_probs[b * 64 + i];
    float tot = pm;
    #pragma unroll
    for (int off = 32; off >= 1; off >>= 1) tot += __shfl_xor(tot, off, 64);
    const float pmlog = logf(fmaxf(pm / fmaxf(tot, EPSF), EPSF));

    const float a = (va > 0.5f) ? agg_g[b * 64 + u] : 0.f;
    float s = a, uc = va;
    #pragma unroll
    for (int off = 32; off >= 1; off >>= 1) {
        s  += __shfl_xor(s,  off, 64);
        uc += __shfl_xor(uc, off, 64);
    }
    const float pb = (s > 0.f) ? (a / fmaxf(s, EPSF)) : (va / fmaxf(uc, 1.f));
    float term = 0.f;
    if (va > 0.5f) {
        const float pbc = fmaxf(pb, EPSF);
        term = pbc * (logf(pbc) - pmlog);
    }
    #pragma unroll
    for (int off = 32; off >= 1; off >>= 1) term += __shfl_down(term, off, 64);
    if (u == 0) atomicAdd(&acc[2], term);
}

// ---------------------------------------------------------------------------
// Small terms + final combine. Single block, 256 threads.
// ---------------------------------------------------------------------------
__global__ __launch_bounds__(256) void e2e3_small(
    const float* __restrict__ selector_probs,   // [256,64]
    const float* __restrict__ selector_onehot,  // [256,64]
    const float* __restrict__ out_rates,        // [48,256]
    const float* __restrict__ trg_rates,        // [50,256]
    const int*   __restrict__ trg_lengths,      // [256]
    const float* __restrict__ acc,              // [4]
    float* __restrict__ out)
{
    const int tid  = threadIdx.x;
    const int wave = tid >> 6;
    const int lane = tid & 63;

    float v_selnum = 0.f, v_selcnt = 0.f, v_ent = 0.f;
    float v_rate = 0.f, v_den = 0.f, v_smooth = 0.f;

    for (int g = tid; g < 512; g += 256) {
        const float* pp = selector_probs  + g * 32;
        const float* oo = selector_onehot + g * 32;
        float p = 0.f, m = 0.f;
        #pragma unroll
        for (int k = 0; k < 32; ++k) { p += pp[k] * oo[k]; m += oo[k]; }
        if (m > 0.5f) { v_selnum += -logf(fmaxf(p, EPSF)); v_selcnt += 1.f; }
    }
    for (int i = tid; i < 256 * 64; i += 256) {
        const float p = fmaxf(selector_probs[i], EPSF);
        v_ent += -p * logf(p);
    }
    for (int i = tid; i < 48 * 256; i += 256)
        v_rate += fabsf(out_rates[i] - trg_rates[i + 256]);
    for (int b2 = tid; b2 < 256; b2 += 256)
        v_den += (float)(trg_lengths[b2] - 2);
    for (int i = tid; i < 47 * 256; i += 256) {
        const int b2 = i & 255;
        const int t  = i >> 8;
        int eff = trg_lengths[b2] - 3; if (eff < 0) eff = 0;
        if (t < eff) v_smooth += fabsf(out_rates[i + 256] - out_rates[i]);
    }

    __shared__ float red[6][4];
    float vals[6] = {v_selnum, v_selcnt, v_ent, v_rate, v_den, v_smooth};
    #pragma unroll
    for (int k = 0; k < 6; ++k) {
        float v = vals[k];
        #pragma unroll
        for (int off = 32; off >= 1; off >>= 1) v += __shfl_down(v, off, 64);
        if (lane == 0) red[k][wave] = v;
    }
    __syncthreads();
    if (tid == 0) {
        float s[6];
        #pragma unroll
        for (int k = 0; k < 6; ++k) s[k] = red[k][0] + red[k][1] + red[k][2] + red[k][3];
        const float loss =
              s[0] / fmaxf(s[1], 1.f)                      // LAM_SEL * loss_sel
            + 10.f * acc[0] / fmaxf(acc[1], 1.f)           // loss_id
            + 5.f  * s[3]   / fmaxf(s[4], 1.f)             // loss_rate
            + 0.1f * acc[2] * (1.f / 256.f)                // loss_kl
            + 0.05f * 0.5f * s[2] * (1.f / 256.f)          // loss_entropy
            + 0.5f * s[5];                                 // loss_smooth
        out[0] = loss;
    }
}

extern "C" void kernel_launch(void* const* d_in, const int* in_sizes, int n_in,
                              void* d_out, int out_size, void* d_ws, size_t ws_size,
                              hipStream_t stream) {
    const float* selector_probs  = (const float*)d_in[1];
    const float* selector_onehot = (const float*)d_in[2];
    const float* out_ids         = (const float*)d_in[3];
    const float* out_rates       = (const float*)d_in[4];
    const float* trg_labels      = (const float*)d_in[5];
    const float* trg_rates       = (const float*)d_in[6];
    const int*   trg_lengths     = (const int*)d_in[7];
    const int*   candi_ids       = (const int*)d_in[8];
    const int*   routes          = (const int*)d_in[9];

    char*  ws    = (char*)d_ws;
    float* acc   = (float*)ws;                 // 16 B
    float* agg_g = (float*)(ws + 256);         // 64 KB

    (void)hipMemsetAsync(ws, 0, 256 + 65536, stream);

    e2e3_stream<<<1024, 512, 0, stream>>>(out_ids, trg_labels, candi_ids,
                                          routes, agg_g, acc);
    e2e3_kl2<<<256, 64, 0, stream>>>(selector_probs, candi_ids, agg_g, acc);
    e2e3_small<<<1, 256, 0, stream>>>(selector_probs, selector_onehot,
                                      out_rates, trg_rates, trg_lengths,
                                      acc, (float*)d_out);
}

// Round 10
// 118.715 us; speedup vs baseline: 1.0066x; 1.0066x over previous
//
#include <hip/hip_runtime.h>
#include <math.h>

#define EPSF 1e-9f

typedef float v4f __attribute__((ext_vector_type(4)));

// ws layout (ALL buffers fully written every launch -> no memset needed):
//   [0)       agg_g4 [4][256][64] float (256 KB)  non-atomic, slot per block
//   [262144)  id_part[1024][8] float2 (64 KB)     per-wave NLL partials
//   [327680)  kl_part[256] float (1 KB)           per-b KL terms

// ---------------------------------------------------------------------------
// Stream: GRID-STRIDE LINEAR. 1024 blocks x 512 thr (4/CU co-resident).
// b = (bid>>1)&255 constant per block; v = (bid&1)*2048 + tid*4 constant per
// lane; per-step advance = 2M floats = 2 t-slabs, 24 steps cover t=0..47.
// Labels pair at +1 slab (row t+1, same b,v); one-hot labels => NLL value is
// the same lane's out float4. Block builds its b's route->slot table in LDS.
// Each b covered by exactly 4 blocks, slot4 = (bid&1) | ((bid>=512)<<1) ->
// agg_g4[slot4][b][:] written NON-atomically (all elements, every launch).
// Per-wave NLL partials -> id_part[bid][wave] (lane 0, non-atomic).
// out_ids: normal loads (L3-resident across replays). labels: nontemporal.
// ---------------------------------------------------------------------------
__global__ __launch_bounds__(512) void e2e3_stream(
    const float* __restrict__ out_ids,        // [48,256,4096]
    const float* __restrict__ trg_labels,     // [50,256,4096]
    const int*   __restrict__ candi_ids,      // [256,64]
    const int*   __restrict__ routes,         // [256,4096]
    float*  __restrict__ agg_g4,              // [4][256][64]
    float2* __restrict__ id_part)             // [1024][8]
{
    const int bid  = blockIdx.x;
    const int tid  = threadIdx.x;
    const int wave = tid >> 6;
    const int lane = tid & 63;

    const int b     = (bid >> 1) & 255;             // constant per block
    const int v     = (bid & 1) * 2048 + tid * 4;   // constant per lane
    const int slot4 = (bid & 1) | (((bid >> 9) & 1) << 1);

    __shared__ int   table[1024];
    __shared__ float agg_s[64];

    // build this b's route->slot table (first-occurrence dedup)
    table[tid]       = 64;
    table[tid + 512] = 64;
    if (tid < 64) agg_s[tid] = 0.f;
    __syncthreads();
    if (tid < 64) atomicMin(&table[candi_ids[b * 64 + tid]], tid);
    __syncthreads();

    // this lane's 4 slots (fixed for all steps)
    const int4 rt = *reinterpret_cast<const int4*>(routes + (size_t)b * 4096 + v);
    const int tu0 = table[rt.x], tu1 = table[rt.y];
    const int tu2 = table[rt.z], tu3 = table[rt.w];

    const size_t STEP = (size_t)2097152;            // floats per step (2 t-slabs)
    const size_t e0   = (size_t)(bid * 512 + tid) * 4;
    const float* op = out_ids + e0;
    const float* lp = trg_labels + e0 + 1048576;    // +1 t-slab => row t+1

    float s0 = 0.f, s1 = 0.f, s2 = 0.f, s3 = 0.f;   // per-lane dist partials
    float idnum = 0.f, idcnt = 0.f;

    v4f oa = *reinterpret_cast<const v4f*>(op);
    v4f la = __builtin_nontemporal_load(reinterpret_cast<const v4f*>(lp));
    v4f ob = *reinterpret_cast<const v4f*>(op + STEP);
    v4f lb = __builtin_nontemporal_load(reinterpret_cast<const v4f*>(lp + STEP));

    for (int s = 0; s < 24; ++s) {
        v4f oc = (v4f)(0.f), lc = (v4f)(0.f);
        if (s < 22) {
            oc = *reinterpret_cast<const v4f*>(op + (size_t)(s + 2) * STEP);
            lc = __builtin_nontemporal_load(
                     reinterpret_cast<const v4f*>(lp + (size_t)(s + 2) * STEP));
        }
        s0 += oa.x; s1 += oa.y; s2 += oa.z; s3 += oa.w;
        if (la.x > 0.5f) { idnum -= logf(fmaxf(oa.x, EPSF)); idcnt += 1.f; }
        if (la.y > 0.5f) { idnum -= logf(fmaxf(oa.y, EPSF)); idcnt += 1.f; }
        if (la.z > 0.5f) { idnum -= logf(fmaxf(oa.z, EPSF)); idcnt += 1.f; }
        if (la.w > 0.5f) { idnum -= logf(fmaxf(oa.w, EPSF)); idcnt += 1.f; }
        oa = ob; la = lb; ob = oc; lb = lc;
    }

    // scatter per-lane dist sums (valid slots only, ~6% density)
    if (tu0 < 64) atomicAdd(&agg_s[tu0], s0);
    if (tu1 < 64) atomicAdd(&agg_s[tu1], s1);
    if (tu2 < 64) atomicAdd(&agg_s[tu2], s2);
    if (tu3 < 64) atomicAdd(&agg_s[tu3], s3);

    // per-wave NLL partials, non-atomic
    #pragma unroll
    for (int off = 32; off >= 1; off >>= 1) {
        idnum += __shfl_down(idnum, off, 64);
        idcnt += __shfl_down(idcnt, off, 64);
    }
    if (lane == 0) id_part[bid * 8 + wave] = make_float2(idnum, idcnt);

    __syncthreads();
    if (tid < 64) agg_g4[((size_t)slot4 * 256 + b) * 64 + tid] = agg_s[tid];
}

// ---------------------------------------------------------------------------
// KL finalize (dedup + Pm + Pb + KL fused): grid 256 x 64 (one wave per b).
// Writes kl_part[b] non-atomically.
// ---------------------------------------------------------------------------
__global__ __launch_bounds__(64) void e2e3_kl2(
    const float* __restrict__ selector_probs,   // [256,64]
    const int*   __restrict__ candi_ids,        // [256,64]
    const float* __restrict__ agg_g4,           // [4][256][64]
    float* __restrict__ kl_part)                // [256]
{
    const int b = blockIdx.x;
    const int u = threadIdx.x;

    __shared__ int table[1024];
    __shared__ int ids_s[64];
    __shared__ int rep_s[64];

    #pragma unroll
    for (int i = 0; i < 16; ++i) table[u + i * 64] = 64;
    ids_s[u] = candi_ids[b * 64 + u];
    __syncthreads();
    atomicMin(&table[ids_s[u]], u);
    __syncthreads();
    const int rep = table[ids_s[u]];
    rep_s[u] = rep;
    const float va = (rep == u) ? 1.f : 0.f;
    __syncthreads();

    // Pm scatter: sum selector probs whose representative is slot u
    float pm = 0.f;
    for (int i = 0; i < 64; ++i)
        if (rep_s[i] == u) pm += selector_probs[b * 64 + i];
    float tot = pm;
    #pragma unroll
    for (int off = 32; off >= 1; off >>= 1) tot += __shfl_xor(tot, off, 64);
    const float pmlog = logf(fmaxf(pm / fmaxf(tot, EPSF), EPSF));

    float a = 0.f;
    if (va > 0.5f) {
        a = agg_g4[((size_t)0 * 256 + b) * 64 + u]
          + agg_g4[((size_t)1 * 256 + b) * 64 + u]
          + agg_g4[((size_t)2 * 256 + b) * 64 + u]
          + agg_g4[((size_t)3 * 256 + b) * 64 + u];
    }
    float s = a, uc = va;
    #pragma unroll
    for (int off = 32; off >= 1; off >>= 1) {
        s  += __shfl_xor(s,  off, 64);
        uc += __shfl_xor(uc, off, 64);
    }
    const float pb = (s > 0.f) ? (a / fmaxf(s, EPSF)) : (va / fmaxf(uc, 1.f));
    float term = 0.f;
    if (va > 0.5f) {
        const float pbc = fmaxf(pb, EPSF);
        term = pbc * (logf(pbc) - pmlog);
    }
    #pragma unroll
    for (int off = 32; off >= 1; off >>= 1) term += __shfl_down(term, off, 64);
    if (u == 0) kl_part[b] = term;
}

// ---------------------------------------------------------------------------
// Small terms + partial sums + final combine. Single block, 256 threads.
// ---------------------------------------------------------------------------
__global__ __launch_bounds__(256) void e2e3_small(
    const float* __restrict__ selector_probs,   // [256,64]
    const float* __restrict__ selector_onehot,  // [256,64]
    const float* __restrict__ out_rates,        // [48,256]
    const float* __restrict__ trg_rates,        // [50,256]
    const int*   __restrict__ trg_lengths,      // [256]
    const float2* __restrict__ id_part,         // [1024*8]
    const float* __restrict__ kl_part,          // [256]
    float* __restrict__ out)
{
    const int tid  = threadIdx.x;
    const int wave = tid >> 6;
    const int lane = tid & 63;

    float v_selnum = 0.f, v_selcnt = 0.f, v_ent = 0.f;
    float v_rate = 0.f, v_den = 0.f, v_smooth = 0.f;
    float v_id = 0.f, v_idc = 0.f, v_kl = 0.f;

    for (int g = tid; g < 512; g += 256) {
        const float* pp = selector_probs  + g * 32;
        const float* oo = selector_onehot + g * 32;
        float p = 0.f, m = 0.f;
        #pragma unroll
        for (int k = 0; k < 32; ++k) { p += pp[k] * oo[k]; m += oo[k]; }
        if (m > 0.5f) { v_selnum += -logf(fmaxf(p, EPSF)); v_selcnt += 1.f; }
    }
    for (int i = tid; i < 256 * 64; i += 256) {
        const float p = fmaxf(selector_probs[i], EPSF);
        v_ent += -p * logf(p);
    }
    for (int i = tid; i < 48 * 256; i += 256)
        v_rate += fabsf(out_rates[i] - trg_rates[i + 256]);
    for (int b2 = tid; b2 < 256; b2 += 256)
        v_den += (float)(trg_lengths[b2] - 2);
    for (int i = tid; i < 47 * 256; i += 256) {
        const int b2 = i & 255;
        const int t  = i >> 8;
        int eff = trg_lengths[b2] - 3; if (eff < 0) eff = 0;
        if (t < eff) v_smooth += fabsf(out_rates[i + 256] - out_rates[i]);
    }
    // NLL + KL partial sums
    for (int i = tid; i < 8192; i += 256) {
        const float2 p = id_part[i];
        v_id  += p.x;
        v_idc += p.y;
    }
    if (tid < 256) v_kl = kl_part[tid];

    __shared__ float red[9][4];
    float vals[9] = {v_selnum, v_selcnt, v_ent, v_rate, v_den, v_smooth,
                     v_id, v_idc, v_kl};
    #pragma unroll
    for (int k = 0; k < 9; ++k) {
        float v = vals[k];
        #pragma unroll
        for (int off = 32; off >= 1; off >>= 1) v += __shfl_down(v, off, 64);
        if (lane == 0) red[k][wave] = v;
    }
    __syncthreads();
    if (tid == 0) {
        float s[9];
        #pragma unroll
        for (int k = 0; k < 9; ++k) s[k] = red[k][0] + red[k][1] + red[k][2] + red[k][3];
        const float loss =
              s[0] / fmaxf(s[1], 1.f)                      // LAM_SEL * loss_sel
            + 10.f * s[6] / fmaxf(s[7], 1.f)               // loss_id
            + 5.f  * s[3] / fmaxf(s[4], 1.f)               // loss_rate
            + 0.1f * s[8] * (1.f / 256.f)                  // loss_kl
            + 0.05f * 0.5f * s[2] * (1.f / 256.f)          // loss_entropy
            + 0.5f * s[5];                                 // loss_smooth
        out[0] = loss;
    }
}

extern "C" void kernel_launch(void* const* d_in, const int* in_sizes, int n_in,
                              void* d_out, int out_size, void* d_ws, size_t ws_size,
                              hipStream_t stream) {
    const float* selector_probs  = (const float*)d_in[1];
    const float* selector_onehot = (const float*)d_in[2];
    const float* out_ids         = (const float*)d_in[3];
    const float* out_rates       = (const float*)d_in[4];
    const float* trg_labels      = (const float*)d_in[5];
    const float* trg_rates       = (const float*)d_in[6];
    const int*   trg_lengths     = (const int*)d_in[7];
    const int*   candi_ids       = (const int*)d_in[8];
    const int*   routes          = (const int*)d_in[9];

    char*   ws      = (char*)d_ws;
    float*  agg_g4  = (float*)ws;                  // 256 KB
    float2* id_part = (float2*)(ws + 262144);      // 64 KB
    float*  kl_part = (float*)(ws + 327680);       // 1 KB

    e2e3_stream<<<1024, 512, 0, stream>>>(out_ids, trg_labels, candi_ids,
                                          routes, agg_g4, id_part);
    e2e3_kl2<<<256, 64, 0, stream>>>(selector_probs, candi_ids, agg_g4, kl_part);
    e2e3_small<<<1, 256, 0, stream>>>(selector_probs, selector_onehot,
                                      out_rates, trg_rates, trg_lengths,
                                      id_part, kl_part, (float*)d_out);
}